// Round 2
// baseline (296.283 us; speedup 1.0000x reference)
//
#include <hip/hip_runtime.h>
#include <hip/hip_bf16.h>

#define BATCH 8192
#define DMODEL 4096
#define NEXP 64

// ============================================================================
// W transpose: Wt[k][e] = W[e][k]   (1 MB, one-time per launch)
// ============================================================================
__global__ __launch_bounds__(256) void transpose_w(const float* __restrict__ W,
                                                   float* __restrict__ Wt)
{
    const int e = threadIdx.x & 63;
    const int kq = threadIdx.x >> 6;                  // 0..3
    const int kbase = blockIdx.x * 64 + kq * 16;
#pragma unroll
    for (int i = 0; i < 16; ++i)
        Wt[(size_t)(kbase + i) * NEXP + e] = W[(size_t)e * DMODEL + kbase + i];
}

// ============================================================================
// Skinny GEMM: lane = row, W row is wave-uniform (scalar loads), no LDS staging.
// grid = 128 row-groups x S k-splits; 4 waves/block do a further 4-way k-split
// reduced through LDS. part[s][row][e] written by wave 0.
// ============================================================================
__global__ __launch_bounds__(256) void gemm_skinny(const float* __restrict__ x,
                                                   const float* __restrict__ Wt,
                                                   float* __restrict__ part,
                                                   int S)
{
    __shared__ float red[3][64][68];   // 52 KB; pad 68 keeps float4 alignment

    const int t = threadIdx.x;
    const int w = t >> 6;
    const int lane = t & 63;
    const int g = blockIdx.x % 128;     // row group
    const int s = blockIdx.x / 128;     // k-split index
    const int row = g * 64 + lane;
    const int kslice = 1024 / S;        // = DMODEL / (4*S)
    const int k0 = (s * 4 + w) * kslice;

    float acc[64];
#pragma unroll
    for (int e = 0; e < 64; ++e) acc[e] = 0.f;

    const float* xr = x + (size_t)row * DMODEL;

    for (int kk = k0; kk < k0 + kslice; kk += 4) {
        const float4 xv = *reinterpret_cast<const float4*>(xr + kk);
        const float xj[4] = {xv.x, xv.y, xv.z, xv.w};
#pragma unroll
        for (int j = 0; j < 4; ++j) {
            const float* wr = Wt + (size_t)(kk + j) * NEXP;   // wave-uniform
#pragma unroll
            for (int q = 0; q < 16; ++q) {
                const float4 wq = *reinterpret_cast<const float4*>(wr + q * 4);
                acc[q * 4 + 0] = fmaf(wq.x, xj[j], acc[q * 4 + 0]);
                acc[q * 4 + 1] = fmaf(wq.y, xj[j], acc[q * 4 + 1]);
                acc[q * 4 + 2] = fmaf(wq.z, xj[j], acc[q * 4 + 2]);
                acc[q * 4 + 3] = fmaf(wq.w, xj[j], acc[q * 4 + 3]);
            }
        }
    }

    // ---- in-block 4-way split-K reduction through LDS
    if (w > 0) {
#pragma unroll
        for (int q = 0; q < 16; ++q)
            *reinterpret_cast<float4*>(&red[w - 1][lane][q * 4]) =
                make_float4(acc[q * 4], acc[q * 4 + 1], acc[q * 4 + 2], acc[q * 4 + 3]);
    }
    __syncthreads();
    if (w == 0) {
#pragma unroll
        for (int q = 0; q < 16; ++q) {
            float4 v = make_float4(acc[q * 4], acc[q * 4 + 1], acc[q * 4 + 2], acc[q * 4 + 3]);
#pragma unroll
            for (int ww = 0; ww < 3; ++ww) {
                const float4 r = *reinterpret_cast<const float4*>(&red[ww][lane][q * 4]);
                v.x += r.x; v.y += r.y; v.z += r.z; v.w += r.w;
            }
            *reinterpret_cast<float4*>(&part[((size_t)s * BATCH + row) * NEXP + q * 4]) = v;
        }
    }
}

// ============================================================================
// Router: sum S partials -> logits; top-2 + softmax weights; softmax accumulation
// ============================================================================
__global__ __launch_bounds__(256) void router2(const float* __restrict__ part,
                                               const float* __restrict__ noise,
                                               float* __restrict__ out,
                                               float* __restrict__ probsum,
                                               float* __restrict__ counts,
                                               int S)
{
    __shared__ float sps[4][64];
    __shared__ float scnt[4][64];

    const int t = threadIdx.x;
    const int w = t >> 6;
    const int lane = t & 63;
    const int wg = blockIdx.x * 4 + w;   // 0..1023

    float* out_idx = out;                 // [8192][2] as float
    float* out_w = out + 16384;           // [8192][2]
    float* out_logits = out + 32768;      // [8192][64]

    float psum_local = 0.f;
    float cnt_local = 0.f;

    for (int r = 0; r < 8; ++r) {
        const int row = wg * 8 + r;
        float l = 0.f;
        for (int s = 0; s < S; ++s)
            l += part[((size_t)s * BATCH + row) * NEXP + lane];
        out_logits[(size_t)row * NEXP + lane] = l;

        const float ny = l + 0.1f * noise[(size_t)row * NEXP + lane];

        // top-1 (value, index), tie -> lower index
        float v1 = ny; int i1 = lane;
#pragma unroll
        for (int m = 32; m >= 1; m >>= 1) {
            float ov = __shfl_xor(v1, m);
            int oi = __shfl_xor(i1, m);
            if (ov > v1 || (ov == v1 && oi < i1)) { v1 = ov; i1 = oi; }
        }
        // top-2: mask out winner
        float v2 = (lane == i1) ? -1e30f : ny; int i2 = lane;
#pragma unroll
        for (int m = 32; m >= 1; m >>= 1) {
            float ov = __shfl_xor(v2, m);
            int oi = __shfl_xor(i2, m);
            if (ov > v2 || (ov == v2 && oi < i2)) { v2 = ov; i2 = oi; }
        }

        if (lane == 0) {
            const float d = expf(v2 - v1);      // v1 >= v2
            const float w1 = 1.0f / (1.0f + d);
            out_idx[row * 2 + 0] = (float)i1;
            out_idx[row * 2 + 1] = (float)i2;
            out_w[row * 2 + 0] = w1;
            out_w[row * 2 + 1] = 1.0f - w1;
        }

        // full softmax over clean logits
        float m = l;
#pragma unroll
        for (int ss = 32; ss >= 1; ss >>= 1) m = fmaxf(m, __shfl_xor(m, ss));
        const float p = expf(l - m);
        float sum = p;
#pragma unroll
        for (int ss = 32; ss >= 1; ss >>= 1) sum += __shfl_xor(sum, ss);
        psum_local += p / sum;
        cnt_local += (lane == i1 ? 1.f : 0.f) + (lane == i2 ? 1.f : 0.f);
    }

    sps[w][lane] = psum_local;
    scnt[w][lane] = cnt_local;
    __syncthreads();
    if (t < 64) {
        float ssum = 0.f, c = 0.f;
#pragma unroll
        for (int ww = 0; ww < 4; ++ww) { ssum += sps[ww][t]; c += scnt[ww][t]; }
        atomicAdd(&probsum[t], ssum);
        atomicAdd(&counts[t], c);
    }
}

// ============================================================================
// Loss
// ============================================================================
__global__ void loss_kernel(const float* __restrict__ probsum,
                            const float* __restrict__ counts,
                            float* __restrict__ out_loss)
{
    const int e = threadIdx.x;
    float v = probsum[e] * counts[e];
#pragma unroll
    for (int s = 32; s >= 1; s >>= 1) v += __shfl_xor(v, s);
    if (e == 0)
        out_loss[0] = (float)NEXP * v / ((float)BATCH * (float)BATCH);
}

// ============================================================================
// Legacy fallback (round-1, proven) for tiny workspace
// ============================================================================
__global__ __launch_bounds__(256) void gemm_legacy(const float* __restrict__ x,
                                                   const float* __restrict__ W,
                                                   float* __restrict__ dst)
{
    __shared__ float As[32 * 68];
    __shared__ float Bs[32 * 68];
    const int t = threadIdx.x;
    const int rbase = blockIdx.x * 64;
    const int ty = t >> 4, tx = t & 15, qs = t & 7, rr0 = t >> 3;
    float acc[4][4] = {};
    for (int kc = 0; kc < DMODEL; kc += 32) {
        __syncthreads();
        {
            const float4 v0 = *reinterpret_cast<const float4*>(&x[(size_t)(rbase + rr0) * DMODEL + kc + qs * 4]);
            const float4 v1 = *reinterpret_cast<const float4*>(&x[(size_t)(rbase + rr0 + 32) * DMODEL + kc + qs * 4]);
            As[(qs * 4 + 0) * 68 + rr0] = v0.x; As[(qs * 4 + 1) * 68 + rr0] = v0.y;
            As[(qs * 4 + 2) * 68 + rr0] = v0.z; As[(qs * 4 + 3) * 68 + rr0] = v0.w;
            As[(qs * 4 + 0) * 68 + rr0 + 32] = v1.x; As[(qs * 4 + 1) * 68 + rr0 + 32] = v1.y;
            As[(qs * 4 + 2) * 68 + rr0 + 32] = v1.z; As[(qs * 4 + 3) * 68 + rr0 + 32] = v1.w;
        }
        {
            const float4 v0 = *reinterpret_cast<const float4*>(&W[(size_t)rr0 * DMODEL + kc + qs * 4]);
            const float4 v1 = *reinterpret_cast<const float4*>(&W[(size_t)(rr0 + 32) * DMODEL + kc + qs * 4]);
            Bs[(qs * 4 + 0) * 68 + rr0] = v0.x; Bs[(qs * 4 + 1) * 68 + rr0] = v0.y;
            Bs[(qs * 4 + 2) * 68 + rr0] = v0.z; Bs[(qs * 4 + 3) * 68 + rr0] = v0.w;
            Bs[(qs * 4 + 0) * 68 + rr0 + 32] = v1.x; Bs[(qs * 4 + 1) * 68 + rr0 + 32] = v1.y;
            Bs[(qs * 4 + 2) * 68 + rr0 + 32] = v1.z; Bs[(qs * 4 + 3) * 68 + rr0 + 32] = v1.w;
        }
        __syncthreads();
#pragma unroll
        for (int k = 0; k < 32; ++k) {
            const float4 a = *reinterpret_cast<const float4*>(&As[k * 68 + ty * 4]);
            const float4 b = *reinterpret_cast<const float4*>(&Bs[k * 68 + tx * 4]);
            const float av[4] = {a.x, a.y, a.z, a.w};
            const float bv[4] = {b.x, b.y, b.z, b.w};
#pragma unroll
            for (int i = 0; i < 4; ++i)
#pragma unroll
                for (int j = 0; j < 4; ++j)
                    acc[i][j] += av[i] * bv[j];
        }
    }
#pragma unroll
    for (int i = 0; i < 4; ++i) {
        const int row = rbase + ty * 4 + i;
        *reinterpret_cast<float4*>(&dst[(size_t)row * NEXP + tx * 4]) =
            make_float4(acc[i][0], acc[i][1], acc[i][2], acc[i][3]);
    }
}

__global__ __launch_bounds__(256) void router_legacy(const float* __restrict__ logits_io,
                                                     const float* __restrict__ noise,
                                                     float* __restrict__ out,
                                                     float* __restrict__ probsum,
                                                     float* __restrict__ counts)
{
    __shared__ float sps[4][64];
    __shared__ float scnt[4][64];
    const int t = threadIdx.x;
    const int w = t >> 6, lane = t & 63;
    const int wg = blockIdx.x * 4 + w;
    float* out_idx = out;
    float* out_w = out + 16384;
    float psum_local = 0.f, cnt_local = 0.f;
    for (int r = 0; r < 8; ++r) {
        const int row = wg * 8 + r;
        const float l = logits_io[(size_t)row * NEXP + lane];
        const float ny = l + 0.1f * noise[(size_t)row * NEXP + lane];
        float v1 = ny; int i1 = lane;
#pragma unroll
        for (int m = 32; m >= 1; m >>= 1) {
            float ov = __shfl_xor(v1, m); int oi = __shfl_xor(i1, m);
            if (ov > v1 || (ov == v1 && oi < i1)) { v1 = ov; i1 = oi; }
        }
        float v2 = (lane == i1) ? -1e30f : ny; int i2 = lane;
#pragma unroll
        for (int m = 32; m >= 1; m >>= 1) {
            float ov = __shfl_xor(v2, m); int oi = __shfl_xor(i2, m);
            if (ov > v2 || (ov == v2 && oi < i2)) { v2 = ov; i2 = oi; }
        }
        if (lane == 0) {
            const float d = expf(v2 - v1);
            const float w1 = 1.0f / (1.0f + d);
            out_idx[row * 2 + 0] = (float)i1; out_idx[row * 2 + 1] = (float)i2;
            out_w[row * 2 + 0] = w1; out_w[row * 2 + 1] = 1.0f - w1;
        }
        float m = l;
#pragma unroll
        for (int ss = 32; ss >= 1; ss >>= 1) m = fmaxf(m, __shfl_xor(m, ss));
        const float p = expf(l - m);
        float sum = p;
#pragma unroll
        for (int ss = 32; ss >= 1; ss >>= 1) sum += __shfl_xor(sum, ss);
        psum_local += p / sum;
        cnt_local += (lane == i1 ? 1.f : 0.f) + (lane == i2 ? 1.f : 0.f);
    }
    sps[w][lane] = psum_local; scnt[w][lane] = cnt_local;
    __syncthreads();
    if (t < 64) {
        float ssum = 0.f, c = 0.f;
#pragma unroll
        for (int ww = 0; ww < 4; ++ww) { ssum += sps[ww][t]; c += scnt[ww][t]; }
        atomicAdd(&probsum[t], ssum);
        atomicAdd(&counts[t], c);
    }
}

// ============================================================================
extern "C" void kernel_launch(void* const* d_in, const int* in_sizes, int n_in,
                              void* d_out, int out_size, void* d_ws, size_t ws_size,
                              hipStream_t stream)
{
    const float* x = (const float*)d_in[0];
    const float* W = (const float*)d_in[1];
    const float* noise = (const float*)d_in[2];
    float* out = (float*)d_out;
    float* ws = (float*)d_ws;

    float* probsum = ws;                   // 64 floats
    float* counts = ws + 64;               // 64 floats
    float* Wt = ws + 256;                  // 4096*64 floats = 1 MB
    float* part = Wt + (size_t)DMODEL * NEXP;

    // pick largest split-K factor that fits the workspace
    int S = 0;
    const size_t base_floats = 256 + (size_t)DMODEL * NEXP;
    for (int cand = 8; cand >= 1; cand >>= 1) {
        const size_t need = (base_floats + (size_t)cand * BATCH * NEXP) * sizeof(float);
        if (ws_size >= need) { S = cand; break; }
    }

    hipMemsetAsync(d_ws, 0, 512, stream);

    if (S >= 1) {
        transpose_w<<<64, 256, 0, stream>>>(W, Wt);
        gemm_skinny<<<128 * S, 256, 0, stream>>>(x, Wt, part, S);
        router2<<<256, 256, 0, stream>>>(part, noise, out, probsum, counts, S);
    } else {
        float* out_logits = out + 32768;
        gemm_legacy<<<128, 256, 0, stream>>>(x, W, out_logits);
        router_legacy<<<256, 256, 0, stream>>>(out_logits, noise, out, probsum, counts);
    }

    loss_kernel<<<1, 64, 0, stream>>>(probsum, counts, out + 557056);
}

// Round 3
// 272.728 us; speedup vs baseline: 1.0864x; 1.0864x over previous
//
#include <hip/hip_runtime.h>
#include <hip/hip_bf16.h>

#define BATCH 8192
#define DMODEL 4096
#define NEXP 64

// ============================================================================
// W transpose: Wt[k][e] = W[e][k]   (1 MB, one-time per launch)
// ============================================================================
__global__ __launch_bounds__(256) void transpose_w(const float* __restrict__ W,
                                                   float* __restrict__ Wt)
{
    const int e = threadIdx.x & 63;
    const int kq = threadIdx.x >> 6;                  // 0..3
    const int kbase = blockIdx.x * 64 + kq * 16;
#pragma unroll
    for (int i = 0; i < 16; ++i)
        Wt[(size_t)(kbase + i) * NEXP + e] = W[(size_t)e * DMODEL + kbase + i];
}

// ============================================================================
// Skinny GEMM, lane = expert.
// Block: 256 threads = 4 waves; each wave owns 16 rows; block tile = 64 rows.
// Per 32-k chunk: Wt[32][64] staged to LDS (8 KB), each lane keeps its expert
// column in wreg[32]; x read at wave-uniform addresses (readfirstlane row base)
// -> scalar/broadcast loads. 512 FMA per wave per chunk dominates.
// Grid = 128 row-groups x S k-splits. part[s][row][e].
// ============================================================================
__global__ __launch_bounds__(256, 4) void gemm_b(const float* __restrict__ x,
                                                 const float* __restrict__ Wt,
                                                 float* __restrict__ part,
                                                 int S)
{
    __shared__ float sW[32 * 64];   // 8 KB

    const int t = threadIdx.x;
    const int lane = t & 63;
    const int g = blockIdx.x & 127;          // row group
    const int s = blockIdx.x >> 7;           // k-split
    const int kbeg = s * (DMODEL / S);
    const int kend = kbeg + (DMODEL / S);

    // wave id forced into an SGPR so all row addresses are provably uniform
    const int wid = __builtin_amdgcn_readfirstlane(t >> 6);
    const int row0 = g * 64 + wid * 16;

    float acc[16];
#pragma unroll
    for (int r = 0; r < 16; ++r) acc[r] = 0.f;

    for (int k0 = kbeg; k0 < kend; k0 += 32) {
        __syncthreads();
        // ---- stage Wt[k0..k0+31][0..63] -> LDS (2048 floats, 8/thread)
        {
            const float4* src = reinterpret_cast<const float4*>(Wt + (size_t)k0 * NEXP);
            const float4 a = src[t];
            const float4 b = src[t + 256];
            reinterpret_cast<float4*>(sW)[t] = a;
            reinterpret_cast<float4*>(sW)[t + 256] = b;
        }
        __syncthreads();

        // ---- each lane: its expert's 32 weights into registers
        float wreg[32];
#pragma unroll
        for (int kk = 0; kk < 32; ++kk)
            wreg[kk] = sW[kk * 64 + lane];      // bank = lane%32 -> 2-way, free

        // ---- 16 rows, wave-uniform x loads
#pragma unroll
        for (int r = 0; r < 16; ++r) {
            const float* xr = x + (size_t)(row0 + r) * DMODEL + k0;   // uniform
            float xv[32];
#pragma unroll
            for (int q = 0; q < 8; ++q) {
                const float4 v = reinterpret_cast<const float4*>(xr)[q];
                xv[4 * q + 0] = v.x; xv[4 * q + 1] = v.y;
                xv[4 * q + 2] = v.z; xv[4 * q + 3] = v.w;
            }
#pragma unroll
            for (int kk = 0; kk < 32; ++kk)
                acc[r] = fmaf(wreg[kk], xv[kk], acc[r]);
        }
    }

    // ---- write partials: coalesced 256B per wave per row
#pragma unroll
    for (int r = 0; r < 16; ++r)
        part[((size_t)s * BATCH + row0 + r) * NEXP + lane] = acc[r];
}

// ============================================================================
// Router: sum S partials -> logits; top-2 + softmax weights; softmax accumulation
// ============================================================================
__global__ __launch_bounds__(256) void router2(const float* __restrict__ part,
                                               const float* __restrict__ noise,
                                               float* __restrict__ out,
                                               float* __restrict__ probsum,
                                               float* __restrict__ counts,
                                               int S)
{
    __shared__ float sps[4][64];
    __shared__ float scnt[4][64];

    const int t = threadIdx.x;
    const int w = t >> 6;
    const int lane = t & 63;
    const int wg = blockIdx.x * 4 + w;   // 0..1023

    float* out_idx = out;                 // [8192][2] as float
    float* out_w = out + 16384;           // [8192][2]
    float* out_logits = out + 32768;      // [8192][64]

    float psum_local = 0.f;
    float cnt_local = 0.f;

    for (int r = 0; r < 8; ++r) {
        const int row = wg * 8 + r;
        float l = 0.f;
        for (int s = 0; s < S; ++s)
            l += part[((size_t)s * BATCH + row) * NEXP + lane];
        out_logits[(size_t)row * NEXP + lane] = l;

        const float ny = l + 0.1f * noise[(size_t)row * NEXP + lane];

        // top-1 (value, index), tie -> lower index
        float v1 = ny; int i1 = lane;
#pragma unroll
        for (int m = 32; m >= 1; m >>= 1) {
            float ov = __shfl_xor(v1, m);
            int oi = __shfl_xor(i1, m);
            if (ov > v1 || (ov == v1 && oi < i1)) { v1 = ov; i1 = oi; }
        }
        // top-2: mask out winner
        float v2 = (lane == i1) ? -1e30f : ny; int i2 = lane;
#pragma unroll
        for (int m = 32; m >= 1; m >>= 1) {
            float ov = __shfl_xor(v2, m);
            int oi = __shfl_xor(i2, m);
            if (ov > v2 || (ov == v2 && oi < i2)) { v2 = ov; i2 = oi; }
        }

        if (lane == 0) {
            const float d = expf(v2 - v1);      // v1 >= v2
            const float w1 = 1.0f / (1.0f + d);
            out_idx[row * 2 + 0] = (float)i1;
            out_idx[row * 2 + 1] = (float)i2;
            out_w[row * 2 + 0] = w1;
            out_w[row * 2 + 1] = 1.0f - w1;
        }

        // full softmax over clean logits
        float m = l;
#pragma unroll
        for (int ss = 32; ss >= 1; ss >>= 1) m = fmaxf(m, __shfl_xor(m, ss));
        const float p = expf(l - m);
        float sum = p;
#pragma unroll
        for (int ss = 32; ss >= 1; ss >>= 1) sum += __shfl_xor(sum, ss);
        psum_local += p / sum;
        cnt_local += (lane == i1 ? 1.f : 0.f) + (lane == i2 ? 1.f : 0.f);
    }

    sps[w][lane] = psum_local;
    scnt[w][lane] = cnt_local;
    __syncthreads();
    if (t < 64) {
        float ssum = 0.f, c = 0.f;
#pragma unroll
        for (int ww = 0; ww < 4; ++ww) { ssum += sps[ww][t]; c += scnt[ww][t]; }
        atomicAdd(&probsum[t], ssum);
        atomicAdd(&counts[t], c);
    }
}

// ============================================================================
// Loss
// ============================================================================
__global__ void loss_kernel(const float* __restrict__ probsum,
                            const float* __restrict__ counts,
                            float* __restrict__ out_loss)
{
    const int e = threadIdx.x;
    float v = probsum[e] * counts[e];
#pragma unroll
    for (int s = 32; s >= 1; s >>= 1) v += __shfl_xor(v, s);
    if (e == 0)
        out_loss[0] = (float)NEXP * v / ((float)BATCH * (float)BATCH);
}

// ============================================================================
extern "C" void kernel_launch(void* const* d_in, const int* in_sizes, int n_in,
                              void* d_out, int out_size, void* d_ws, size_t ws_size,
                              hipStream_t stream)
{
    const float* x = (const float*)d_in[0];
    const float* W = (const float*)d_in[1];
    const float* noise = (const float*)d_in[2];
    float* out = (float*)d_out;
    float* ws = (float*)d_ws;

    float* probsum = ws;                   // 64 floats
    float* counts = ws + 64;               // 64 floats
    float* Wt = ws + 256;                  // 4096*64 floats = 1 MB
    float* part = Wt + (size_t)DMODEL * NEXP;

    // pick largest split-K factor that fits the workspace (round-2 proved S=8 fits)
    int S = 1;
    const size_t base_floats = 256 + (size_t)DMODEL * NEXP;
    for (int cand = 8; cand >= 1; cand >>= 1) {
        const size_t need = (base_floats + (size_t)cand * BATCH * NEXP) * sizeof(float);
        if (ws_size >= need) { S = cand; break; }
    }

    hipMemsetAsync(d_ws, 0, 512, stream);

    transpose_w<<<64, 256, 0, stream>>>(W, Wt);
    gemm_b<<<128 * S, 256, 0, stream>>>(x, Wt, part, S);
    router2<<<256, 256, 0, stream>>>(part, noise, out, probsum, counts, S);
    loss_kernel<<<1, 64, 0, stream>>>(probsum, counts, out + 557056);
}

// Round 4
// 139.243 us; speedup vs baseline: 2.1278x; 1.9586x over previous
//
#include <hip/hip_runtime.h>
#include <hip/hip_bf16.h>

#define BATCH 8192
#define DMODEL 4096
#define NEXP 64

#define APITCH 129   // LDS row pitch for A tile (floats)
#define BPITCH 65    // LDS row pitch for B tile (floats)

// ============================================================================
// W transpose: Wt[k][e] = W[e][k]   (1 MB, one-time per launch)
// ============================================================================
__global__ __launch_bounds__(256) void transpose_w(const float* __restrict__ W,
                                                   float* __restrict__ Wt)
{
    const int e = threadIdx.x & 63;
    const int kq = threadIdx.x >> 6;                  // 0..3
    const int kbase = blockIdx.x * 64 + kq * 16;
#pragma unroll
    for (int i = 0; i < 16; ++i)
        Wt[(size_t)(kbase + i) * NEXP + e] = W[(size_t)e * DMODEL + kbase + i];
}

// ============================================================================
// GEMM: 128x64 tile, BK=32, 128 threads, 8x8 register blocking, split-K.
// As[k][row] (pitch 129), Bs[k][e] (pitch 65). part[s][row][e].
// ============================================================================
__global__ __launch_bounds__(128, 4) void gemm_c(const float* __restrict__ x,
                                                 const float* __restrict__ Wt,
                                                 float* __restrict__ part,
                                                 int S)
{
    __shared__ float As[32 * APITCH];   // 16.1 KB
    __shared__ float Bs[32 * BPITCH];   // 8.1 KB

    const int t = threadIdx.x;          // 0..127
    const int g = blockIdx.x;           // row group 0..63
    const int s = blockIdx.y;           // k-split
    const int kslice = DMODEL / S;
    const int kbeg = s * kslice;

    const int trow = t >> 3;            // 0..15 -> rows trow*8..+7
    const int tcol = t & 7;             // 0..7  -> experts tcol*8..+7

    const int srow = t >> 3;            // staging row lane 0..15
    const int skq = t & 7;              // staging k-quad

    float acc[8][8] = {};

    for (int k0 = kbeg; k0 < kbeg + kslice; k0 += 32) {
        __syncthreads();
        // ---- stage A: x[g*128 .. +127][k0..k0+31] -> As[k][row]
#pragma unroll
        for (int p = 0; p < 8; ++p) {
            const int row = srow + p * 16;
            const float4 v = *reinterpret_cast<const float4*>(
                &x[(size_t)(g * 128 + row) * DMODEL + k0 + skq * 4]);
            As[(skq * 4 + 0) * APITCH + row] = v.x;
            As[(skq * 4 + 1) * APITCH + row] = v.y;
            As[(skq * 4 + 2) * APITCH + row] = v.z;
            As[(skq * 4 + 3) * APITCH + row] = v.w;
        }
        // ---- stage B: Wt[k0..k0+31][0..63] -> Bs[k][e]  (direct copy, b128)
#pragma unroll
        for (int p = 0; p < 4; ++p) {
            const int idx = t + p * 128;        // 0..511
            const int k = idx >> 4;             // 0..31
            const int e4 = (idx & 15) * 4;
            const float4 v = *reinterpret_cast<const float4*>(
                &Wt[(size_t)(k0 + k) * NEXP + e4]);
            *reinterpret_cast<float4*>(&Bs[k * BPITCH + e4]) = v;
        }
        __syncthreads();

        // ---- compute: 32 k-steps, 8x8 outer product
#pragma unroll
        for (int k = 0; k < 32; ++k) {
            const float4 a0 = *reinterpret_cast<const float4*>(&As[k * APITCH + trow * 8]);
            const float4 a1 = *reinterpret_cast<const float4*>(&As[k * APITCH + trow * 8 + 4]);
            const float4 b0 = *reinterpret_cast<const float4*>(&Bs[k * BPITCH + tcol * 8]);
            const float4 b1 = *reinterpret_cast<const float4*>(&Bs[k * BPITCH + tcol * 8 + 4]);
            const float av[8] = {a0.x, a0.y, a0.z, a0.w, a1.x, a1.y, a1.z, a1.w};
            const float bv[8] = {b0.x, b0.y, b0.z, b0.w, b1.x, b1.y, b1.z, b1.w};
#pragma unroll
            for (int i = 0; i < 8; ++i)
#pragma unroll
                for (int j = 0; j < 8; ++j)
                    acc[i][j] = fmaf(av[i], bv[j], acc[i][j]);
        }
    }

    // ---- write partials
#pragma unroll
    for (int i = 0; i < 8; ++i) {
        const int row = g * 128 + trow * 8 + i;
        float* dst = &part[((size_t)s * BATCH + row) * NEXP + tcol * 8];
        *reinterpret_cast<float4*>(dst) =
            make_float4(acc[i][0], acc[i][1], acc[i][2], acc[i][3]);
        *reinterpret_cast<float4*>(dst + 4) =
            make_float4(acc[i][4], acc[i][5], acc[i][6], acc[i][7]);
    }
}

// ============================================================================
// Router: sum S partials -> logits; top-2 + softmax weights; softmax accumulation
// ============================================================================
__global__ __launch_bounds__(256) void router2(const float* __restrict__ part,
                                               const float* __restrict__ noise,
                                               float* __restrict__ out,
                                               float* __restrict__ probsum,
                                               float* __restrict__ counts,
                                               int S)
{
    __shared__ float sps[4][64];
    __shared__ float scnt[4][64];

    const int t = threadIdx.x;
    const int w = t >> 6;
    const int lane = t & 63;
    const int wg = blockIdx.x * 4 + w;   // 0..1023

    float* out_idx = out;                 // [8192][2] as float
    float* out_w = out + 16384;           // [8192][2]
    float* out_logits = out + 32768;      // [8192][64]

    float psum_local = 0.f;
    float cnt_local = 0.f;

    for (int r = 0; r < 8; ++r) {
        const int row = wg * 8 + r;
        float l = 0.f;
        for (int s = 0; s < S; ++s)
            l += part[((size_t)s * BATCH + row) * NEXP + lane];
        out_logits[(size_t)row * NEXP + lane] = l;

        const float ny = l + 0.1f * noise[(size_t)row * NEXP + lane];

        // top-1 (value, index), tie -> lower index
        float v1 = ny; int i1 = lane;
#pragma unroll
        for (int m = 32; m >= 1; m >>= 1) {
            float ov = __shfl_xor(v1, m);
            int oi = __shfl_xor(i1, m);
            if (ov > v1 || (ov == v1 && oi < i1)) { v1 = ov; i1 = oi; }
        }
        // top-2: mask out winner
        float v2 = (lane == i1) ? -1e30f : ny; int i2 = lane;
#pragma unroll
        for (int m = 32; m >= 1; m >>= 1) {
            float ov = __shfl_xor(v2, m);
            int oi = __shfl_xor(i2, m);
            if (ov > v2 || (ov == v2 && oi < i2)) { v2 = ov; i2 = oi; }
        }

        if (lane == 0) {
            const float d = expf(v2 - v1);      // v1 >= v2
            const float w1 = 1.0f / (1.0f + d);
            out_idx[row * 2 + 0] = (float)i1;
            out_idx[row * 2 + 1] = (float)i2;
            out_w[row * 2 + 0] = w1;
            out_w[row * 2 + 1] = 1.0f - w1;
        }

        // full softmax over clean logits
        float m = l;
#pragma unroll
        for (int ss = 32; ss >= 1; ss >>= 1) m = fmaxf(m, __shfl_xor(m, ss));
        const float p = expf(l - m);
        float sum = p;
#pragma unroll
        for (int ss = 32; ss >= 1; ss >>= 1) sum += __shfl_xor(sum, ss);
        psum_local += p / sum;
        cnt_local += (lane == i1 ? 1.f : 0.f) + (lane == i2 ? 1.f : 0.f);
    }

    sps[w][lane] = psum_local;
    scnt[w][lane] = cnt_local;
    __syncthreads();
    if (t < 64) {
        float ssum = 0.f, c = 0.f;
#pragma unroll
        for (int ww = 0; ww < 4; ++ww) { ssum += sps[ww][t]; c += scnt[ww][t]; }
        atomicAdd(&probsum[t], ssum);
        atomicAdd(&counts[t], c);
    }
}

// ============================================================================
// Loss
// ============================================================================
__global__ void loss_kernel(const float* __restrict__ probsum,
                            const float* __restrict__ counts,
                            float* __restrict__ out_loss)
{
    const int e = threadIdx.x;
    float v = probsum[e] * counts[e];
#pragma unroll
    for (int s = 32; s >= 1; s >>= 1) v += __shfl_xor(v, s);
    if (e == 0)
        out_loss[0] = (float)NEXP * v / ((float)BATCH * (float)BATCH);
}

// ============================================================================
extern "C" void kernel_launch(void* const* d_in, const int* in_sizes, int n_in,
                              void* d_out, int out_size, void* d_ws, size_t ws_size,
                              hipStream_t stream)
{
    const float* x = (const float*)d_in[0];
    const float* W = (const float*)d_in[1];
    const float* noise = (const float*)d_in[2];
    float* out = (float*)d_out;
    float* ws = (float*)d_ws;

    float* probsum = ws;                   // 64 floats
    float* counts = ws + 64;               // 64 floats
    float* Wt = ws + 256;                  // 4096*64 floats = 1 MB
    float* part = Wt + (size_t)DMODEL * NEXP;

    // pick largest split-K factor that fits the workspace (>=17.8 MB proven for S=8)
    int S = 1;
    const size_t base_floats = 256 + (size_t)DMODEL * NEXP;
    for (int cand = 16; cand >= 1; cand >>= 1) {
        const size_t need = (base_floats + (size_t)cand * BATCH * NEXP) * sizeof(float);
        if (ws_size >= need) { S = cand; break; }
    }

    hipMemsetAsync(d_ws, 0, 512, stream);

    transpose_w<<<64, 256, 0, stream>>>(W, Wt);
    gemm_c<<<dim3(64, S), 128, 0, stream>>>(x, Wt, part, S);
    router2<<<256, 256, 0, stream>>>(part, noise, out, probsum, counts, S);
    loss_kernel<<<1, 64, 0, stream>>>(probsum, counts, out + 557056);
}

// Round 6
// 88.537 us; speedup vs baseline: 3.3464x; 1.5727x over previous
//
#include <hip/hip_runtime.h>
#include <hip/hip_bf16.h>

#define BATCH 8192
#define DMODEL 4096
#define NEXP 64

typedef __attribute__((ext_vector_type(8))) short short8;   // 8 bf16 (4 VGPR)
typedef __attribute__((ext_vector_type(4))) float f32x4;

#define WF_PLANE 262144   // ushorts per plane: 128 ksteps * 4 cfrags * 64 lanes * 8
#define WF_FLOATS 393216  // 3 planes * 262144 ushorts / 2 = floats occupied by WF

// ============================================================================
// Build W planes (h/m/l bf16 split) in MFMA B-fragment order:
// WF[plane][ks][cf][lane][j] <- bf16 split of W[e = cf*16 + (l&15)][k = ks*32 + (l>>4)*8 + j]
// ============================================================================
__global__ __launch_bounds__(256) void build_wf(const float* __restrict__ W,
                                                unsigned short* __restrict__ WF)
{
    const int gid = blockIdx.x * 256 + threadIdx.x;   // 0..32767
    const int ks = gid >> 8;
    const int cf = (gid >> 6) & 3;
    const int l  = gid & 63;
    const int e  = cf * 16 + (l & 15);
    const int k0 = ks * 32 + (l >> 4) * 8;
    const float* src = W + (size_t)e * DMODEL + k0;

    unsigned short hu[8], mu[8], lu[8];
#pragma unroll
    for (int j = 0; j < 8; ++j) {
        const float xv = src[j];
        const __hip_bfloat16 h = __float2bfloat16(xv);
        const float r1 = xv - __bfloat162float(h);
        const __hip_bfloat16 m = __float2bfloat16(r1);
        const float r2 = r1 - __bfloat162float(m);
        const __hip_bfloat16 lo = __float2bfloat16(r2);
        hu[j] = __builtin_bit_cast(unsigned short, h);
        mu[j] = __builtin_bit_cast(unsigned short, m);
        lu[j] = __builtin_bit_cast(unsigned short, lo);
    }
    const size_t off = ((size_t)(ks * 4 + cf) * 64 + l) * 8;
#pragma unroll
    for (int j = 0; j < 8; ++j) {
        WF[off + j] = hu[j];
        WF[WF_PLANE + off + j] = mu[j];
        WF[2 * WF_PLANE + off + j] = lu[j];
    }
}

// ============================================================================
// MFMA GEMM: 1 wave per block, 32 rows x 64 experts, no LDS, no barriers.
// 6-product bf16 split (hH,hM,mH,hL,lH,mM) == fp32-accurate logits.
// Grid = 256 row-groups x S k-splits.  part[s][row][e].
// ============================================================================

#define CVT1(V, J, AH, AM, AL) {                                              \
    const float xv_ = (V);                                                    \
    const __hip_bfloat16 h_ = __float2bfloat16(xv_);                          \
    const float r1_ = xv_ - __bfloat162float(h_);                             \
    const __hip_bfloat16 m_ = __float2bfloat16(r1_);                          \
    const float r2_ = r1_ - __bfloat162float(m_);                             \
    const __hip_bfloat16 l_ = __float2bfloat16(r2_);                          \
    AH[J] = (short)__builtin_bit_cast(unsigned short, h_);                    \
    AM[J] = (short)__builtin_bit_cast(unsigned short, m_);                    \
    AL[J] = (short)__builtin_bit_cast(unsigned short, l_); }

#define CVT8(X0, X1, AH, AM, AL)                                              \
    CVT1(X0[0], 0, AH, AM, AL) CVT1(X0[1], 1, AH, AM, AL)                     \
    CVT1(X0[2], 2, AH, AM, AL) CVT1(X0[3], 3, AH, AM, AL)                     \
    CVT1(X1[0], 4, AH, AM, AL) CVT1(X1[1], 5, AH, AM, AL)                     \
    CVT1(X1[2], 6, AH, AM, AL) CVT1(X1[3], 7, AH, AM, AL)

#define LOADSET(XA, XB, BB, STEP) {                                           \
    const float* pa_ = xr0 + (size_t)(STEP) * 32;                             \
    XA[0] = *(const f32x4*)pa_;  XA[1] = *(const f32x4*)(pa_ + 4);            \
    const float* pb_ = xr1 + (size_t)(STEP) * 32;                             \
    XB[0] = *(const f32x4*)pb_;  XB[1] = *(const f32x4*)(pb_ + 4);            \
    const unsigned short* wp_ = wf0 + (size_t)(STEP) * 2048;                  \
    _Pragma("unroll")                                                         \
    for (int cf_ = 0; cf_ < 4; ++cf_) {                                       \
        BB[cf_][0] = *(const short8*)(wp_ + cf_ * 512);                       \
        BB[cf_][1] = *(const short8*)(wp_ + WF_PLANE + cf_ * 512);            \
        BB[cf_][2] = *(const short8*)(wp_ + 2 * WF_PLANE + cf_ * 512);        \
    } }

#define MFMA(A, B, C) __builtin_amdgcn_mfma_f32_16x16x32_bf16(A, B, C, 0, 0, 0)

#define COMPUTESET(XA, XB, BB) {                                              \
    short8 ah0, am0, al0, ah1, am1, al1;                                      \
    CVT8(XA[0], XA[1], ah0, am0, al0)                                         \
    CVT8(XB[0], XB[1], ah1, am1, al1)                                         \
    _Pragma("unroll")                                                         \
    for (int cf_ = 0; cf_ < 4; ++cf_) {                                       \
        const short8 bh = BB[cf_][0];                                         \
        const short8 bm = BB[cf_][1];                                         \
        const short8 bl = BB[cf_][2];                                         \
        acc[0][cf_] = MFMA(ah0, bh, acc[0][cf_]);                             \
        acc[0][cf_] = MFMA(ah0, bm, acc[0][cf_]);                             \
        acc[0][cf_] = MFMA(am0, bh, acc[0][cf_]);                             \
        acc[0][cf_] = MFMA(ah0, bl, acc[0][cf_]);                             \
        acc[0][cf_] = MFMA(al0, bh, acc[0][cf_]);                             \
        acc[0][cf_] = MFMA(am0, bm, acc[0][cf_]);                             \
        acc[1][cf_] = MFMA(ah1, bh, acc[1][cf_]);                             \
        acc[1][cf_] = MFMA(ah1, bm, acc[1][cf_]);                             \
        acc[1][cf_] = MFMA(am1, bh, acc[1][cf_]);                             \
        acc[1][cf_] = MFMA(ah1, bl, acc[1][cf_]);                             \
        acc[1][cf_] = MFMA(al1, bh, acc[1][cf_]);                             \
        acc[1][cf_] = MFMA(am1, bm, acc[1][cf_]);                             \
    } }

__global__ __launch_bounds__(64, 2) void gemm_mfma(const float* __restrict__ x,
                                                   const unsigned short* __restrict__ WF,
                                                   float* __restrict__ part,
                                                   int S)
{
    const int l = threadIdx.x;             // 0..63
    const int g = blockIdx.x & 255;        // row group (32 rows); groups == 256
    const int s = blockIdx.x >> 8;         // k-split
    const int rowbase = g * 32;
    const int kbeg = s * (DMODEL / S);
    const int nsteps = (DMODEL / S) >> 5;  // 32-k steps (even for S in {1,2,4,8})

    const int lr = l & 15;                 // row (A) / col (B,C) within frag
    const int lk = l >> 4;                 // k-chunk 0..3

    const float* xr0 = x + (size_t)(rowbase + lr) * DMODEL + kbeg + lk * 8;
    const float* xr1 = xr0 + (size_t)16 * DMODEL;
    const unsigned short* wf0 = WF + (size_t)(kbeg >> 5) * 2048 + l * 8;

    f32x4 acc[2][4] = {};

    f32x4 xa0[2], xb0[2], xa1[2], xb1[2];
    short8 b0[4][3], b1[4][3];

    LOADSET(xa0, xb0, b0, 0);
    for (int it = 0; it < nsteps; it += 2) {
        LOADSET(xa1, xb1, b1, it + 1);
        COMPUTESET(xa0, xb0, b0);
        if (it + 2 < nsteps) LOADSET(xa0, xb0, b0, it + 2);
        COMPUTESET(xa1, xb1, b1);
    }

    // C write: col = lr, row = (l>>4)*4 + reg  (m89-verified layout)
    const int orow = lk * 4;
#pragma unroll
    for (int rf = 0; rf < 2; ++rf)
#pragma unroll
        for (int j = 0; j < 4; ++j) {
            const int row = rowbase + rf * 16 + orow + j;
            float* dst = part + ((size_t)s * BATCH + row) * NEXP + lr;
#pragma unroll
            for (int cf = 0; cf < 4; ++cf)
                dst[cf * 16] = acc[rf][cf][j];
        }
}

// ============================================================================
// Router: sum S partials -> logits; top-2 + softmax weights; softmax accumulation
// ============================================================================
__global__ __launch_bounds__(256) void router2(const float* __restrict__ part,
                                               const float* __restrict__ noise,
                                               float* __restrict__ out,
                                               float* __restrict__ probsum,
                                               float* __restrict__ counts,
                                               int S)
{
    __shared__ float sps[4][64];
    __shared__ float scnt[4][64];

    const int t = threadIdx.x;
    const int w = t >> 6;
    const int lane = t & 63;
    const int wg = blockIdx.x * 4 + w;   // 0..1023

    float* out_idx = out;                 // [8192][2] as float
    float* out_w = out + 16384;           // [8192][2]
    float* out_logits = out + 32768;      // [8192][64]

    float psum_local = 0.f;
    float cnt_local = 0.f;

    for (int r = 0; r < 8; ++r) {
        const int row = wg * 8 + r;
        float lgt = 0.f;
        for (int s = 0; s < S; ++s)
            lgt += part[((size_t)s * BATCH + row) * NEXP + lane];
        out_logits[(size_t)row * NEXP + lane] = lgt;

        const float ny = lgt + 0.1f * noise[(size_t)row * NEXP + lane];

        // top-1 (value, index), tie -> lower index
        float v1 = ny; int i1 = lane;
#pragma unroll
        for (int m = 32; m >= 1; m >>= 1) {
            float ov = __shfl_xor(v1, m);
            int oi = __shfl_xor(i1, m);
            if (ov > v1 || (ov == v1 && oi < i1)) { v1 = ov; i1 = oi; }
        }
        // top-2: mask out winner
        float v2 = (lane == i1) ? -1e30f : ny; int i2 = lane;
#pragma unroll
        for (int m = 32; m >= 1; m >>= 1) {
            float ov = __shfl_xor(v2, m);
            int oi = __shfl_xor(i2, m);
            if (ov > v2 || (ov == v2 && oi < i2)) { v2 = ov; i2 = oi; }
        }

        if (lane == 0) {
            const float d = expf(v2 - v1);      // v1 >= v2
            const float w1 = 1.0f / (1.0f + d);
            out_idx[row * 2 + 0] = (float)i1;
            out_idx[row * 2 + 1] = (float)i2;
            out_w[row * 2 + 0] = w1;
            out_w[row * 2 + 1] = 1.0f - w1;
        }

        // full softmax over clean logits
        float m = lgt;
#pragma unroll
        for (int ss = 32; ss >= 1; ss >>= 1) m = fmaxf(m, __shfl_xor(m, ss));
        const float p = expf(lgt - m);
        float sum = p;
#pragma unroll
        for (int ss = 32; ss >= 1; ss >>= 1) sum += __shfl_xor(sum, ss);
        psum_local += p / sum;
        cnt_local += (lane == i1 ? 1.f : 0.f) + (lane == i2 ? 1.f : 0.f);
    }

    sps[w][lane] = psum_local;
    scnt[w][lane] = cnt_local;
    __syncthreads();
    if (t < 64) {
        float ssum = 0.f, c = 0.f;
#pragma unroll
        for (int ww = 0; ww < 4; ++ww) { ssum += sps[ww][t]; c += scnt[ww][t]; }
        atomicAdd(&probsum[t], ssum);
        atomicAdd(&counts[t], c);
    }
}

// ============================================================================
// Loss
// ============================================================================
__global__ void loss_kernel(const float* __restrict__ probsum,
                            const float* __restrict__ counts,
                            float* __restrict__ out_loss)
{
    const int e = threadIdx.x;
    float v = probsum[e] * counts[e];
#pragma unroll
    for (int s = 32; s >= 1; s >>= 1) v += __shfl_xor(v, s);
    if (e == 0)
        out_loss[0] = (float)NEXP * v / ((float)BATCH * (float)BATCH);
}

// ============================================================================
extern "C" void kernel_launch(void* const* d_in, const int* in_sizes, int n_in,
                              void* d_out, int out_size, void* d_ws, size_t ws_size,
                              hipStream_t stream)
{
    const float* x = (const float*)d_in[0];
    const float* W = (const float*)d_in[1];
    const float* noise = (const float*)d_in[2];
    float* out = (float*)d_out;
    float* ws = (float*)d_ws;

    float* probsum = ws;                                   // 64 floats
    float* counts = ws + 64;                               // 64 floats
    unsigned short* WF = (unsigned short*)(ws + 256);      // 1.5 MB = 393216 floats
    float* part = ws + 256 + WF_FLOATS;                    // S * 8192 * 64 floats

    // pick largest split-K factor that fits the workspace
    int S = 1;
    const size_t base_floats = 256 + WF_FLOATS;
    for (int cand = 8; cand >= 1; cand >>= 1) {
        const size_t need = (base_floats + (size_t)cand * BATCH * NEXP) * sizeof(float);
        if (ws_size >= need) { S = cand; break; }
    }

    hipMemsetAsync(d_ws, 0, 512, stream);

    build_wf<<<128, 256, 0, stream>>>(W, WF);
    gemm_mfma<<<256 * S, 64, 0, stream>>>(x, WF, part, S);
    router2<<<256, 256, 0, stream>>>(part, noise, out, probsum, counts, S);
    loss_kernel<<<1, 64, 0, stream>>>(probsum, counts, out + 557056);
}